// Round 1
// baseline (157.825 us; speedup 1.0000x reference)
//
#include <hip/hip_runtime.h>

#define BB 16
#define CC 4
#define HH 736
#define WW 736
#define HWSZ (HH * WW)            // 541696
#define NSEG 64
#define TPB 256
#define PXT 4                     // pixels per thread
#define CHUNK (TPB * PXT)         // 1024
#define NCHUNK (HWSZ / CHUNK)     // 529 exactly
#define SIGMA_AGG 0.5f

// ws layout: [0 .. BB*NSEG*5) floats: per-batch acc[l*5 + c], acc[l*5+4] = card
//            then one int: maxlab of last batch image
#define ACC_FLOATS (BB * NSEG * 5)

__global__ __launch_bounds__(TPB) void k_seg(const int* __restrict__ labels,
                                             const float* __restrict__ pred,
                                             float* __restrict__ acc,
                                             int* __restrict__ maxlab)
{
    __shared__ float s_acc[NSEG * 5];
    __shared__ int s_max;
    const int tid = threadIdx.x;
    const int b = blockIdx.y;
    const long pix = (long)blockIdx.x * CHUNK + tid * PXT;

    for (int i = tid; i < NSEG * 5; i += TPB) s_acc[i] = 0.0f;
    if (tid == 0) s_max = 0;
    __syncthreads();

    const int4 lab = *reinterpret_cast<const int4*>(labels + (long)b * HWSZ + pix);
    const int lmax = max(max(lab.x, lab.y), max(lab.z, lab.w));

    if (lmax > 0) {
        const long pbase = (long)b * CC * HWSZ + pix;
        const float4 p0 = *reinterpret_cast<const float4*>(pred + pbase);
        const float4 p1 = *reinterpret_cast<const float4*>(pred + pbase + (long)HWSZ);
        const float4 p2 = *reinterpret_cast<const float4*>(pred + pbase + 2L * HWSZ);
        const float4 p3 = *reinterpret_cast<const float4*>(pred + pbase + 3L * HWSZ);

        const int   ls[PXT] = {lab.x, lab.y, lab.z, lab.w};
        const float c0[PXT] = {p0.x, p0.y, p0.z, p0.w};
        const float c1[PXT] = {p1.x, p1.y, p1.z, p1.w};
        const float c2[PXT] = {p2.x, p2.y, p2.z, p2.w};
        const float c3[PXT] = {p3.x, p3.y, p3.z, p3.w};

        #pragma unroll
        for (int k = 0; k < PXT; ++k) {
            const int l = ls[k];
            if (l > 0) {
                atomicAdd(&s_acc[l * 5 + 0], c0[k]);
                atomicAdd(&s_acc[l * 5 + 1], c1[k]);
                atomicAdd(&s_acc[l * 5 + 2], c2[k]);
                atomicAdd(&s_acc[l * 5 + 3], c3[k]);
                atomicAdd(&s_acc[l * 5 + 4], 1.0f);
            }
        }
        if (b == BB - 1) atomicMax(&s_max, lmax);
    }
    __syncthreads();

    float* g = acc + (long)b * NSEG * 5;
    for (int i = tid; i < NSEG * 5; i += TPB) {
        const float v = s_acc[i];
        if (v != 0.0f) atomicAdd(&g[i], v);
    }
    if (tid == 0 && b == BB - 1 && s_max > 0) atomicMax(maxlab, s_max);
}

__global__ __launch_bounds__(TPB) void k_loss(const int* __restrict__ labels,
                                              const float* __restrict__ pred,
                                              const float* __restrict__ rmask,
                                              const float* __restrict__ acc,
                                              const int* __restrict__ maxlab,
                                              float* __restrict__ out)
{
    const int tid = threadIdx.x;
    const int b = blockIdx.y;
    const long pix = (long)blockIdx.x * CHUNK + tid * PXT;
    const long base = (long)b * HWSZ + pix;

    const int4   lab = *reinterpret_cast<const int4*>(labels + base);
    const float4 rm  = *reinterpret_cast<const float4*>(rmask + base);

    const long pbase = (long)b * CC * HWSZ + pix;
    const float4 p0 = *reinterpret_cast<const float4*>(pred + pbase);
    const float4 p1 = *reinterpret_cast<const float4*>(pred + pbase + (long)HWSZ);
    const float4 p2 = *reinterpret_cast<const float4*>(pred + pbase + 2L * HWSZ);
    const float4 p3 = *reinterpret_cast<const float4*>(pred + pbase + 3L * HWSZ);

    const int   ls[PXT] = {lab.x, lab.y, lab.z, lab.w};
    const float rr[PXT] = {rm.x, rm.y, rm.z, rm.w};
    const float c0[PXT] = {p0.x, p0.y, p0.z, p0.w};
    const float c1[PXT] = {p1.x, p1.y, p1.z, p1.w};
    const float c2[PXT] = {p2.x, p2.y, p2.z, p2.w};
    const float c3[PXT] = {p3.x, p3.y, p3.z, p3.w};

    const float* g = acc + (long)b * NSEG * 5;

    float local = 0.0f;
    #pragma unroll
    for (int k = 0; k < PXT; ++k) {
        float d0 = c0[k] * rr[k];
        float d1 = c1[k] * rr[k];
        float d2 = c2[k] * rr[k];
        float d3 = c3[k] * rr[k];
        const int l = ls[k];
        if (l > 0) {
            const float* gg = g + l * 5;
            const float inv = 1.0f / (gg[4] + 1.0f);
            d0 -= gg[0] * inv;
            d1 -= gg[1] * inv;
            d2 -= gg[2] * inv;
            d3 -= gg[3] * inv;
        }
        const float ss = d0 * d0 + d1 * d1 + d2 * d2 + d3 * d3;
        const float n  = sqrtf(ss);
        const float d  = fmaxf(n - SIGMA_AGG, 0.0f);
        local += logf(d * d + 1.0f);
    }

    // wave-64 reduction
    #pragma unroll
    for (int off = 32; off > 0; off >>= 1)
        local += __shfl_down(local, off, 64);

    __shared__ float s_part[TPB / 64];
    if ((tid & 63) == 0) s_part[tid >> 6] = local;
    __syncthreads();
    if (tid == 0) {
        float s = 0.0f;
        #pragma unroll
        for (int w = 0; w < TPB / 64; ++w) s += s_part[w];
        atomicAdd(out, s / (float)(*maxlab));
    }
}

extern "C" void kernel_launch(void* const* d_in, const int* in_sizes, int n_in,
                              void* d_out, int out_size, void* d_ws, size_t ws_size,
                              hipStream_t stream) {
    const float* pred   = (const float*)d_in[0];
    const float* rmask  = (const float*)d_in[1];
    // d_in[2] = kernels_mask: redundant (== labels > 0), unused
    const int*   labels = (const int*)d_in[3];

    float* acc    = (float*)d_ws;
    int*   maxlab = (int*)((char*)d_ws + ACC_FLOATS * sizeof(float));
    float* out    = (float*)d_out;

    hipMemsetAsync(d_ws, 0, ACC_FLOATS * sizeof(float) + sizeof(int), stream);
    hipMemsetAsync(d_out, 0, sizeof(float), stream);

    dim3 grid(NCHUNK, BB);
    k_seg<<<grid, TPB, 0, stream>>>(labels, pred, acc, maxlab);
    k_loss<<<grid, TPB, 0, stream>>>(labels, pred, rmask, acc, maxlab, out);
}

// Round 2
// 69.792 us; speedup vs baseline: 2.2614x; 2.2614x over previous
//
#include <hip/hip_runtime.h>

#define BB 16
#define CC 4
#define HWSZ 541696           // 736*736 = 1024*529
#define NSEG 64
#define TPB 256
#define PXT 4                 // pixels per thread per chunk
#define CHUNK (TPB * PXT)     // 1024
#define NCH 529               // chunks per image
#define GX 133                // grid.x; each block does NIT chunks strided by GX
#define NIT 4                 // 133*4 = 532 >= 529 (tail-checked)
#define SIGMA_AGG 0.5f
#define ACC_FLOATS (BB * NSEG * 5)

// ---------------- phase 1: segment sums ----------------
__global__ __launch_bounds__(TPB) void k_seg(const int* __restrict__ labels,
                                             const float* __restrict__ pred,
                                             float* __restrict__ acc,
                                             int* __restrict__ maxlab)
{
    __shared__ float s_acc[NSEG * 5];
    __shared__ int s_max;
    const int tid = threadIdx.x;
    const int b = blockIdx.y;

    for (int i = tid; i < NSEG * 5; i += TPB) s_acc[i] = 0.0f;
    if (tid == 0) s_max = 0;
    __syncthreads();

    const long lbase = (long)b * HWSZ;
    const long pbase = (long)b * CC * HWSZ;

    // prefetch first label quad
    long pix = (long)blockIdx.x * CHUNK + tid * PXT;
    int4 lab = *reinterpret_cast<const int4*>(labels + lbase + pix);

    #pragma unroll
    for (int it = 0; it < NIT; ++it) {
        const int ch_next = blockIdx.x + (it + 1) * GX;
        const bool have_next = (it + 1 < NIT) && (ch_next < NCH);
        const long pix_next = (long)ch_next * CHUNK + tid * PXT;
        int4 lab_next = lab;
        if (have_next)
            lab_next = *reinterpret_cast<const int4*>(labels + lbase + pix_next);

        const int lmax = max(max(lab.x, lab.y), max(lab.z, lab.w));
        if (lmax > 0) {
            const float4 p0 = *reinterpret_cast<const float4*>(pred + pbase + pix);
            const float4 p1 = *reinterpret_cast<const float4*>(pred + pbase + (long)HWSZ + pix);
            const float4 p2 = *reinterpret_cast<const float4*>(pred + pbase + 2L * HWSZ + pix);
            const float4 p3 = *reinterpret_cast<const float4*>(pred + pbase + 3L * HWSZ + pix);

            if (lab.x == lab.y && lab.x == lab.z && lab.x == lab.w) {
                // uniform foreground quad: 5 atomics instead of 20
                float* s = &s_acc[lab.x * 5];
                atomicAdd(s + 0, p0.x + p0.y + p0.z + p0.w);
                atomicAdd(s + 1, p1.x + p1.y + p1.z + p1.w);
                atomicAdd(s + 2, p2.x + p2.y + p2.z + p2.w);
                atomicAdd(s + 3, p3.x + p3.y + p3.z + p3.w);
                atomicAdd(s + 4, 4.0f);
            } else {
                const int ls[4] = {lab.x, lab.y, lab.z, lab.w};
                #pragma unroll
                for (int k = 0; k < 4; ++k) {
                    const int l = ls[k];
                    if (l > 0) {
                        float* s = &s_acc[l * 5];
                        atomicAdd(s + 0, reinterpret_cast<const float*>(&p0)[k]);
                        atomicAdd(s + 1, reinterpret_cast<const float*>(&p1)[k]);
                        atomicAdd(s + 2, reinterpret_cast<const float*>(&p2)[k]);
                        atomicAdd(s + 3, reinterpret_cast<const float*>(&p3)[k]);
                        atomicAdd(s + 4, 1.0f);
                    }
                }
            }
            if (b == BB - 1) atomicMax(&s_max, lmax);
        }
        lab = lab_next;
        pix = pix_next;
        if (!have_next && it + 1 < NIT) break;
    }
    __syncthreads();

    float* g = acc + (long)b * NSEG * 5;
    for (int i = tid; i < NSEG * 5; i += TPB) {
        const float v = s_acc[i];
        if (v != 0.0f) atomicAdd(&g[i], v);
    }
    if (tid == 0 && b == BB - 1 && s_max > 0) atomicMax(maxlab, s_max);
}

// ---------------- phase 2: loss ----------------
struct Pack {
    int4 lab;
    float4 rm, p0, p1, p2, p3;
};

__device__ inline Pack load_pack(const int* __restrict__ labels,
                                 const float* __restrict__ rmask,
                                 const float* __restrict__ pred,
                                 long lbase, long pbase, long pix)
{
    Pack P;
    P.lab = *reinterpret_cast<const int4*>(labels + lbase + pix);
    P.rm  = *reinterpret_cast<const float4*>(rmask + lbase + pix);
    P.p0  = *reinterpret_cast<const float4*>(pred + pbase + pix);
    P.p1  = *reinterpret_cast<const float4*>(pred + pbase + (long)HWSZ + pix);
    P.p2  = *reinterpret_cast<const float4*>(pred + pbase + 2L * HWSZ + pix);
    P.p3  = *reinterpret_cast<const float4*>(pred + pbase + 3L * HWSZ + pix);
    return P;
}

__device__ inline float comp(const Pack& P, const float4* __restrict__ t4)
{
    const int ls[4] = {P.lab.x, P.lab.y, P.lab.z, P.lab.w};
    float res = 0.0f;
    #pragma unroll
    for (int k = 0; k < 4; ++k) {
        const float rr = reinterpret_cast<const float*>(&P.rm)[k];
        const float4 t = t4[ls[k]];           // t4[0] == 0 -> branch-free bg
        const float d0 = reinterpret_cast<const float*>(&P.p0)[k] * rr - t.x;
        const float d1 = reinterpret_cast<const float*>(&P.p1)[k] * rr - t.y;
        const float d2 = reinterpret_cast<const float*>(&P.p2)[k] * rr - t.z;
        const float d3 = reinterpret_cast<const float*>(&P.p3)[k] * rr - t.w;
        const float ss = d0 * d0 + d1 * d1 + d2 * d2 + d3 * d3;
        const float n  = sqrtf(ss);
        const float d  = fmaxf(n - SIGMA_AGG, 0.0f);
        res += __logf(d * d + 1.0f);
    }
    return res;
}

__global__ __launch_bounds__(TPB) void k_loss(const int* __restrict__ labels,
                                              const float* __restrict__ pred,
                                              const float* __restrict__ rmask,
                                              const float* __restrict__ acc,
                                              const int* __restrict__ maxlab,
                                              float* __restrict__ out)
{
    __shared__ __align__(16) float s_t[NSEG * 4];
    const int tid = threadIdx.x;
    const int b = blockIdx.y;

    // build Gk table: t[l][c] = l>0 ? sum/(card+1) : 0
    {
        const float* ab = acc + (long)b * NSEG * 5;
        const int l = tid >> 2, c = tid & 3;
        s_t[tid] = (l > 0) ? ab[l * 5 + c] / (ab[l * 5 + 4] + 1.0f) : 0.0f;
    }
    __syncthreads();
    const float4* t4 = reinterpret_cast<const float4*>(s_t);

    const long lbase = (long)b * HWSZ;
    const long pbase = (long)b * CC * HWSZ;

    float local = 0.0f;
    long pix = (long)blockIdx.x * CHUNK + tid * PXT;
    Pack A = load_pack(labels, rmask, pred, lbase, pbase, pix);

    #pragma unroll
    for (int it = 0; it < NIT; ++it) {
        const int ch_next = blockIdx.x + (it + 1) * GX;
        const bool have_next = (it + 1 < NIT) && (ch_next < NCH);
        Pack B = A;
        if (have_next)
            B = load_pack(labels, rmask, pred, lbase, pbase, (long)ch_next * CHUNK + tid * PXT);
        local += comp(A, t4);
        A = B;
        if (!have_next && it + 1 < NIT) break;
    }

    // wave-64 butterfly + block reduce
    #pragma unroll
    for (int off = 32; off > 0; off >>= 1)
        local += __shfl_xor(local, off, 64);

    __shared__ float s_part[TPB / 64];
    if ((tid & 63) == 0) s_part[tid >> 6] = local;
    __syncthreads();
    if (tid == 0) {
        float s = s_part[0] + s_part[1] + s_part[2] + s_part[3];
        atomicAdd(out, s / (float)(*maxlab));
    }
}

extern "C" void kernel_launch(void* const* d_in, const int* in_sizes, int n_in,
                              void* d_out, int out_size, void* d_ws, size_t ws_size,
                              hipStream_t stream) {
    const float* pred   = (const float*)d_in[0];
    const float* rmask  = (const float*)d_in[1];
    // d_in[2] = kernels_mask: redundant (== labels > 0), unused
    const int*   labels = (const int*)d_in[3];

    float* acc    = (float*)d_ws;
    int*   maxlab = (int*)((char*)d_ws + ACC_FLOATS * sizeof(float));
    float* out    = (float*)d_out;

    hipMemsetAsync(d_ws, 0, ACC_FLOATS * sizeof(float) + sizeof(int), stream);
    hipMemsetAsync(d_out, 0, sizeof(float), stream);

    dim3 grid(GX, BB);
    k_seg<<<grid, TPB, 0, stream>>>(labels, pred, acc, maxlab);
    k_loss<<<grid, TPB, 0, stream>>>(labels, pred, rmask, acc, maxlab, out);
}